// Round 7
// baseline (187.256 us; speedup 1.0000x reference)
//
#include <hip/hip_runtime.h>

typedef unsigned short u16;
typedef unsigned int u32;

#define DM 1024
#define NH 16
#define DH 64
#define BB 2
#define TT 2048

// Q pre-scale: (1/sqrt(64)) * log2(e)
#define SCLQ 0.18033688f

using frag8  = __attribute__((ext_vector_type(8))) short;
using bf16x8 = __attribute__((ext_vector_type(8))) __bf16;
using f32x4  = __attribute__((ext_vector_type(4))) float;

__device__ inline u16 f2bf(float f) {
  union { float f; u32 u; } v; v.f = f;
  u32 r = v.u + 0x7fffu + ((v.u >> 16) & 1u);
  return (u16)(r >> 16);
}

__device__ inline f32x4 mfma_bf16(frag8 a, frag8 b, f32x4 c) {
  return __builtin_amdgcn_mfma_f32_16x16x32_bf16(
      __builtin_bit_cast(bf16x8, a), __builtin_bit_cast(bf16x8, b), c, 0, 0, 0);
}

// async global->LDS, 16B/lane; LDS dest = base + lane*16 (wave-uniform base)
__device__ inline void gld16(void* lds, const void* g) {
  __builtin_amdgcn_global_load_lds(
      (const __attribute__((address_space(1))) void*)g,
      (__attribute__((address_space(3))) void*)lds, 16, 0, 0);
}

// swizzled LDS index (u16 units): row = 8 chunks of 8 u16 (16B);
// stored chunk position = chunk ^ (row & 7)
__device__ inline int swi(int row, int chunk) {
  return row * 64 + ((chunk ^ (row & 7)) << 3);
}

// 128-wide tile index (u16 units), 16 chunks of 8 u16; low-3 chunk bits XOR row
__device__ inline int sidx128(int row, int col) {
  return row * 128 + ((((col >> 3) ^ (row & 7)) << 3) | (col & 7));
}

// ---------- fused prep: x -> bf16 (blocks 0..4095) + W transposes (4096..5119) ----------
__global__ __launch_bounds__(256) void prep_kernel(
    const float* __restrict__ X, u16* __restrict__ Y,
    const float* __restrict__ W0, const float* __restrict__ W1,
    const float* __restrict__ W2, const float* __restrict__ W3,
    u16* __restrict__ O0, u16* __restrict__ O1,
    u16* __restrict__ O2, u16* __restrict__ O3) {
  int tid = threadIdx.x;
  if (blockIdx.x < 4096) {
    int i = blockIdx.x * 256 + tid;
    float4 v = ((const float4*)X)[i];
    ushort4 o;
    o.x = f2bf(v.x); o.y = f2bf(v.y); o.z = f2bf(v.z); o.w = f2bf(v.w);
    ((ushort4*)Y)[i] = o;
    return;
  }
  int id = blockIdx.x - 4096;          // 0..1023
  int z = id >> 8;                     // 0..3
  int rem = id & 255;
  const float* W; u16* Ot;
  switch (z) {
    case 0: W = W0; Ot = O0; break;
    case 1: W = W1; Ot = O1; break;
    case 2: W = W2; Ot = O2; break;
    default: W = W3; Ot = O3; break;
  }
  __shared__ u16 Ls[64][72];
  int n0 = (rem & 15) * 64;
  int k0 = (rem >> 4) * 64;
#pragma unroll
  for (int p = 0; p < 4; ++p) {
    int iid = tid + p * 256;
    int row = iid >> 4;
    int c4 = (iid & 15) * 4;
    float4 v = *(const float4*)&W[(size_t)(k0 + row) * DM + n0 + c4];
    ushort4 o; o.x = f2bf(v.x); o.y = f2bf(v.y); o.z = f2bf(v.z); o.w = f2bf(v.w);
    *(ushort4*)&Ls[row][c4] = o;
  }
  __syncthreads();
#pragma unroll
  for (int p = 0; p < 4; ++p) {
    int iid = tid + p * 256;
    int row = iid >> 4;
    int c4 = (iid & 15) * 4;
    ushort4 o;
    o.x = Ls[c4 + 0][row]; o.y = Ls[c4 + 1][row];
    o.z = Ls[c4 + 2][row]; o.w = Ls[c4 + 3][row];
    *(ushort4*)&Ot[(size_t)(n0 + row) * DM + k0 + c4] = o;
  }
}

// ---------- QKV GEMM: 128x128 tile, 3-deep counted-vmcnt pipeline ----------
__global__ __launch_bounds__(256, 3) void gemm_qkv_kernel(
    const u16* __restrict__ A, const u16* __restrict__ Bt,
    const float* __restrict__ b0, const float* __restrict__ b1,
    const float* __restrict__ b2,
    u16* __restrict__ QK, u16* __restrict__ Vt) {
  constexpr int K = 1024;
  constexpr int NT = 32;
  __shared__ u16 sm[24576];      // As: 3 x 4096, Bs: 3 x 4096 (48 KB); epi: 16384
  int tid = threadIdx.x;
  int lane = tid & 63, w = tid >> 6;
  int qd = lane >> 4, ln = lane & 15;
  int wm = (w & 1) * 64, wn = (w >> 1) * 64;
  // XCD-chunked remap: xcd -> 8M x 12N supertile; bijective over 32x24 grid.
  int lin = blockIdx.y * 24 + blockIdx.x;
  int xcd = lin & 7, j = lin >> 3;             // j in 0..95
  int m_idx = ((xcd >> 1) << 3) | (j & 7);     // 0..31
  int n_idx = (xcd & 1) * 12 + (j >> 3);       // 0..23
  int m0 = m_idx * 128, n0 = n_idx * 128;
  f32x4 z = {0.f, 0.f, 0.f, 0.f};
  f32x4 acc[4][4];
#pragma unroll
  for (int mi = 0; mi < 4; ++mi)
#pragma unroll
    for (int ni = 0; ni < 4; ++ni) acc[mi][ni] = z;

  const u16* ga = A + (size_t)(m0 + w * 32 + (lane >> 2)) * K + (lane & 3) * 8;
  const u16* gb = Bt + (size_t)(n0 + w * 32 + (lane >> 2)) * K + (lane & 3) * 8;

  auto stage = [&](int t, int buf) {
    u16* Ab = sm + buf * 4096;
    u16* Bb = sm + 12288 + buf * 4096;
    gld16(&Ab[w * 1024],       ga + t * 32);
    gld16(&Ab[w * 1024 + 512], ga + t * 32 + 16 * K);
    gld16(&Bb[w * 1024],       gb + t * 32);
    gld16(&Bb[w * 1024 + 512], gb + t * 32 + 16 * K);
  };

  stage(0, 0);
  stage(1, 1);

  int cur = 0, nbuf = 2;
  for (int t = 0; t < NT; ++t) {
    if (t < NT - 1) {
      asm volatile("s_waitcnt vmcnt(4)" ::: "memory");
    } else {
      asm volatile("s_waitcnt vmcnt(0)" ::: "memory");
    }
    __builtin_amdgcn_sched_barrier(0);
    __builtin_amdgcn_s_barrier();
    if (t + 2 < NT) {
      stage(t + 2, nbuf);
      nbuf = (nbuf == 2) ? 0 : nbuf + 1;
    }
    const u16* Ab = sm + cur * 4096;
    const u16* Bb = sm + 12288 + cur * 4096;
    frag8 af[4], bfr[4];
#pragma unroll
    for (int mi = 0; mi < 4; ++mi)
      af[mi] = *(const frag8*)&Ab[(wm + mi * 16 + ln) * 32 + qd * 8];
#pragma unroll
    for (int ni = 0; ni < 4; ++ni)
      bfr[ni] = *(const frag8*)&Bb[(wn + ni * 16 + ln) * 32 + qd * 8];
    __builtin_amdgcn_s_setprio(1);
#pragma unroll
    for (int mi = 0; mi < 4; ++mi)
#pragma unroll
      for (int ni = 0; ni < 4; ++ni)
        acc[mi][ni] = mfma_bf16(af[mi], bfr[ni], acc[mi][ni]);
    __builtin_amdgcn_s_setprio(0);
    cur = (cur == 2) ? 0 : cur + 1;
  }

  __syncthreads();  // done reading staging buffers; sm is free for the epilogue

  if (n0 < 2048) {
    bool isq = (n0 < 1024);
#pragma unroll
    for (int ni = 0; ni < 4; ++ni) {
      int c_loc = wn + ni * 16 + ln;
      int col = n0 + c_loc;
      float bias = isq ? b0[col] : b1[col - 1024];
#pragma unroll
      for (int mi = 0; mi < 4; ++mi) {
        int rbase = wm + mi * 16 + qd * 4;
#pragma unroll
        for (int r = 0; r < 4; ++r) {
          float v = acc[mi][ni][r] + bias;
          if (isq) v *= SCLQ;
          sm[sidx128(rbase + r, c_loc)] = f2bf(v);
        }
      }
    }
    __syncthreads();
#pragma unroll
    for (int p = 0; p < 8; ++p) {
      int id = p * 256 + tid;
      int tr = id >> 4, cr = id & 15;
      uint4 v = *(const uint4*)&sm[tr * 128 + ((cr ^ (tr & 7)) << 3)];
      *(uint4*)&QK[(size_t)(m0 + tr) * 2048 + n0 + cr * 8] = v;
    }
  } else {
    int b = m0 >> 11, tb = m0 & 2047;
    int n0v = n0 - 2048;
#pragma unroll
    for (int ni = 0; ni < 4; ++ni) {
      int c_loc = wn + ni * 16 + ln;       // d index within 128-col block
      float bias = b2[n0v + c_loc];
#pragma unroll
      for (int mi = 0; mi < 4; ++mi) {
        int tbase = wm + mi * 16 + qd * 4;
        u32 lo = ((u32)f2bf(acc[mi][ni][1] + bias) << 16) | f2bf(acc[mi][ni][0] + bias);
        u32 hi = ((u32)f2bf(acc[mi][ni][3] + bias) << 16) | f2bf(acc[mi][ni][2] + bias);
        uint2 pk; pk.x = lo; pk.y = hi;
        int idx = c_loc * 128 + ((((tbase >> 3) ^ (c_loc & 7)) << 3) | (tbase & 7));
        *(uint2*)&sm[idx] = pk;
      }
    }
    __syncthreads();
#pragma unroll
    for (int p = 0; p < 8; ++p) {
      int id = p * 256 + tid;
      int d_loc = id >> 4, tc = id & 15;
      uint4 v = *(const uint4*)&sm[d_loc * 128 + ((tc ^ (d_loc & 7)) << 3)];
      *(uint4*)&Vt[(size_t)(b * 1024 + n0v + d_loc) * 2048 + tb + tc * 8] = v;
    }
  }
}

// ---------- out-proj GEMM: 128x64 tile, 3-deep counted-vmcnt pipeline ----------
__global__ __launch_bounds__(256) void gemm_out_kernel(
    const u16* __restrict__ A, const u16* __restrict__ Bt,
    const float* __restrict__ b0, float* __restrict__ Cf) {
  constexpr int K = 1024;
  constexpr int NT = 32;
  __shared__ u16 sm[18432];    // As: 3 x 4096, Bs: 3 x 2048 (36 KB)
  int tid = threadIdx.x;
  int lane = tid & 63, w = tid >> 6;
  int qd = lane >> 4, ln = lane & 15;
  int lin = blockIdx.y * 16 + blockIdx.x;
  int xcd = lin & 7, j = lin >> 3;             // j in 0..63
  int m_idx = ((xcd >> 1) << 3) | (j & 7);     // 0..31
  int n_idx = ((xcd & 1) << 3) | (j >> 3);     // 0..15
  int m0 = m_idx * 128, n0 = n_idx * 64;
  f32x4 z = {0.f, 0.f, 0.f, 0.f};
  f32x4 acc[2][4];
#pragma unroll
  for (int mi = 0; mi < 2; ++mi)
#pragma unroll
    for (int ni = 0; ni < 4; ++ni) acc[mi][ni] = z;

  const u16* ga = A + (size_t)(m0 + w * 32 + (lane >> 2)) * K + (lane & 3) * 8;
  const u16* gb = Bt + (size_t)(n0 + w * 16 + (lane >> 2)) * K + (lane & 3) * 8;

  auto stage = [&](int t, int buf) {
    u16* Ab = sm + buf * 4096;
    u16* Bb = sm + 12288 + buf * 2048;
    gld16(&Ab[w * 1024],       ga + t * 32);
    gld16(&Ab[w * 1024 + 512], ga + t * 32 + 16 * K);
    gld16(&Bb[w * 512],        gb + t * 32);
  };

  stage(0, 0);
  stage(1, 1);

  int cur = 0, nbuf = 2;
  for (int t = 0; t < NT; ++t) {
    if (t < NT - 1) {
      asm volatile("s_waitcnt vmcnt(3)" ::: "memory");
    } else {
      asm volatile("s_waitcnt vmcnt(0)" ::: "memory");
    }
    __builtin_amdgcn_sched_barrier(0);
    __builtin_amdgcn_s_barrier();
    if (t + 2 < NT) {
      stage(t + 2, nbuf);
      nbuf = (nbuf == 2) ? 0 : nbuf + 1;
    }
    const u16* Ab = sm + cur * 4096;
    const u16* Bb = sm + 12288 + cur * 2048;
    frag8 af[2], bfr[4];
#pragma unroll
    for (int mi = 0; mi < 2; ++mi)
      af[mi] = *(const frag8*)&Ab[(w * 32 + mi * 16 + ln) * 32 + qd * 8];
#pragma unroll
    for (int ni = 0; ni < 4; ++ni)
      bfr[ni] = *(const frag8*)&Bb[(ni * 16 + ln) * 32 + qd * 8];
    __builtin_amdgcn_s_setprio(1);
#pragma unroll
    for (int mi = 0; mi < 2; ++mi)
#pragma unroll
      for (int ni = 0; ni < 4; ++ni)
        acc[mi][ni] = mfma_bf16(af[mi], bfr[ni], acc[mi][ni]);
    __builtin_amdgcn_s_setprio(0);
    cur = (cur == 2) ? 0 : cur + 1;
  }

#pragma unroll
  for (int ni = 0; ni < 4; ++ni) {
    int col = n0 + ni * 16 + ln;
    float bias = b0[col];
#pragma unroll
    for (int mi = 0; mi < 2; ++mi) {
      int row = m0 + w * 32 + mi * 16 + qd * 4;
#pragma unroll
      for (int r = 0; r < 4; ++r)
        Cf[(size_t)(row + r) * 1024 + col] = acc[mi][ni][r] + bias;
    }
  }
}

// ---------- flash v9: QBLK=128, 8-wave blocks — 2x work per barrier/staging ----------
// flash v8 ran ~4x above its MFMA floor: per 64-row q-tile a wave did only 16
// MFMA but paid a full K/V staging + 2 barrier syncs + the serial exp2 chain.
// v9 keeps the per-wave program IDENTICAL (16 q-rows each) but blocks are now
// 8 waves covering 128 q-rows: block-iters drop 16896 -> 8704, K/V staging
// traffic and barrier count halve. LDS 48KB (K16+V16+Ps16), 2 blk/CU -> same
// 16 waves/CU. Remap: per XCD, CU c hosts slots {qt=a, qt=15-a} (nkt sum 34,
// uniform; bijective). Diag: last two kv-tiles; wave-slot (w>>2) vs jt gives
// {full | none | diag with w'=w&3} — diag path identical to v8's 4-wave logic.
// QK: [B*T][2048] bf16 (Q pre-scaled, K). Vt: [B*H][DH][TT]. O: [B*T][1024] bf16.
__global__ __launch_bounds__(512, 4) void flash9_kernel(const u16* __restrict__ QK,
                                                        const u16* __restrict__ Vt,
                                                        u16* __restrict__ O) {
  int lin = blockIdx.x;              // 512 blocks
  int xcd = lin & 7, u = lin >> 3;   // u in 0..63
  int sl = u >> 5, c = u & 31;       // slot 0/1, CU 0..31
  int bh = xcd * 4 + ((sl << 1) | (c >> 4));
  int qt = sl ? (15 - (c & 15)) : (c & 15);   // q-tile of 128 rows, 0..15
  int b = bh >> 4, h = bh & 15;
  int q0 = qt * 128;
  __shared__ u16 Ks[2 * 4096];       // [buf][64 kv x 64 d]
  __shared__ u16 Vs[2 * 4096];       // [buf][64 d x 64 t]
  __shared__ u16 Ps[8192];           // [128 q x 64 kv]
  int tid = threadIdx.x;
  int lane = tid & 63, w = tid >> 6; // w 0..7
  int qd = lane >> 4, ln = lane & 15;
  int wsl = w >> 2, wl = w & 3;

  // Q fragments (B-operand: n=ln -> q, k=qd*8+j -> d); Q pre-scaled by SCLQ
  frag8 qf[2];
#pragma unroll
  for (int kk = 0; kk < 2; ++kk)
    qf[kk] = *(const frag8*)&QK[(size_t)(b * TT + q0 + w * 16 + ln) * 2048 +
                                h * 64 + kk * 32 + qd * 8];

  // swizzled global_load_lds staging: each wave stages 8 rows (1 gld16 each of K,V)
  int lr = lane >> 3, lc = (lane & 7) ^ lr;
  const u16* Kg = &QK[(size_t)(b * TT + w * 8 + lr) * 2048 + 1024 + h * 64 + lc * 8];
  const u16* Vg = &Vt[(size_t)(bh * 64 + w * 8 + lr) * 2048 + lc * 8];
  int ldsw = w * 512;

  int nkt = 2 * qt + 2;

  gld16(&Ks[ldsw], Kg);
  gld16(&Vs[ldsw], Vg);

  float l = 0.f;
  f32x4 z = {0.f, 0.f, 0.f, 0.f};
  f32x4 o[4] = {z, z, z, z};

  for (int kt = 0; kt < nkt; ++kt) {
    int cur = kt & 1;
    int cb = cur * 4096;
    __syncthreads();  // drains prefetch for buf[cur]; prior reads of buf[cur^1] done

    if (kt + 1 < nkt) {
      int nb = (cur ^ 1) * 4096;
      size_t ko = (size_t)(kt + 1) * 64 * 2048;
      int vo = (kt + 1) * 64;
      gld16(&Ks[nb + ldsw], Kg + ko);
      gld16(&Vs[nb + ldsw], Vg + vo);
    }

    int jt = kt - 2 * qt;                     // >=0 only in diag region (jt in {0,1})
    bool dreg = (jt >= 0);
    bool none = dreg && (jt == 1) && (wsl == 0);  // kv entirely above this wave's q
    bool diag = dreg && (wsl == jt);

    // S^T = K Q^T
    f32x4 s[4] = {z, z, z, z};
    if (!none) {
      __builtin_amdgcn_s_setprio(1);
#pragma unroll
      for (int mi = 0; mi < 4; ++mi) {
        if (diag && mi > wl) continue;  // fully-masked k-rows
#pragma unroll
        for (int kk = 0; kk < 2; ++kk) {
          frag8 ak = *(const frag8*)&Ks[cb + swi(mi * 16 + ln, 4 * kk + qd)];
          s[mi] = mfma_bf16(ak, qf[kk], s[mi]);
        }
      }
      __builtin_amdgcn_s_setprio(0);
    }

    // fixed-max softmax + manual RNE bf16 pack into P^T LDS (own-wave rows only)
#pragma unroll
    for (int mi = 0; mi < 4; ++mi) {
      int pb = swi(w * 16 + ln, 2 * mi + (qd >> 1)) + (qd & 1) * 4;
      if (none || (diag && mi > wl)) {
        uint2 zz; zz.x = 0u; zz.y = 0u;
        *(uint2*)&Ps[pb] = zz;
        continue;
      }
      float p0 = __builtin_amdgcn_exp2f(s[mi][0]);
      float p1 = __builtin_amdgcn_exp2f(s[mi][1]);
      float p2 = __builtin_amdgcn_exp2f(s[mi][2]);
      float p3 = __builtin_amdgcn_exp2f(s[mi][3]);
      if (diag && mi == wl) {
        p0 = (qd * 4 + 0 <= ln) ? p0 : 0.f;
        p1 = (qd * 4 + 1 <= ln) ? p1 : 0.f;
        p2 = (qd * 4 + 2 <= ln) ? p2 : 0.f;
        p3 = (qd * 4 + 3 <= ln) ? p3 : 0.f;
      }
      l += (p0 + p1) + (p2 + p3);
      u32 u0 = __builtin_bit_cast(u32, p0) + 0x8000u;
      u32 u1 = __builtin_bit_cast(u32, p1) + 0x8000u;
      u32 u2 = __builtin_bit_cast(u32, p2) + 0x8000u;
      u32 u3 = __builtin_bit_cast(u32, p3) + 0x8000u;
      uint2 pk;
      pk.x = __builtin_amdgcn_perm(u1, u0, 0x07060302u);
      pk.y = __builtin_amdgcn_perm(u3, u2, 0x07060302u);
      *(uint2*)&Ps[pb] = pk;
    }

    // O^T += V^T P^T
    if (!none) {
      __builtin_amdgcn_s_setprio(1);
#pragma unroll
      for (int kk = 0; kk < 2; ++kk) {
        if (diag && kk == 1 && wl < 2) continue;  // fully-masked k-half
        frag8 bp = *(const frag8*)&Ps[swi(w * 16 + ln, 4 * kk + qd)];
#pragma unroll
        for (int mi = 0; mi < 4; ++mi) {
          frag8 av = *(const frag8*)&Vs[cb + swi(mi * 16 + ln, 4 * kk + qd)];
          o[mi] = mfma_bf16(av, bp, o[mi]);
        }
      }
      __builtin_amdgcn_s_setprio(0);
    }
  }

  l += __shfl_xor(l, 16);
  l += __shfl_xor(l, 32);
  float rl = 1.0f / l;

#pragma unroll
  for (int mi = 0; mi < 4; ++mi) {
    ushort4 ov;
    ov.x = f2bf(o[mi][0] * rl); ov.y = f2bf(o[mi][1] * rl);
    ov.z = f2bf(o[mi][2] * rl); ov.w = f2bf(o[mi][3] * rl);
    *(ushort4*)&O[(size_t)(b * TT + q0 + w * 16 + ln) * DM + h * 64 + mi * 16 + qd * 4] = ov;
  }
}

extern "C" void kernel_launch(void* const* d_in, const int* in_sizes, int n_in,
                              void* d_out, int out_size, void* d_ws, size_t ws_size,
                              hipStream_t stream) {
  const float* x  = (const float*)d_in[0];
  const float* Wq = (const float*)d_in[1];
  const float* bq = (const float*)d_in[2];
  const float* Wk = (const float*)d_in[3];
  const float* bk = (const float*)d_in[4];
  const float* Wv = (const float*)d_in[5];
  const float* bv = (const float*)d_in[6];
  const float* Wo = (const float*)d_in[7];
  const float* bo = (const float*)d_in[8];

  char* ws = (char*)d_ws;
  const size_t MB = 1ull << 20;
  u16* xbf  = (u16*)(ws + 0);         // 8 MB  (4096 x 1024)
  u16* Wcat = (u16*)(ws + 8 * MB);    // 6 MB  (3072 x 1024: Wq^T|Wk^T|Wv^T)
  u16* Wot  = (u16*)(ws + 14 * MB);   // 2 MB
  u16* QKb  = (u16*)(ws + 16 * MB);   // 16 MB (4096 x 2048)
  u16* Vtb  = (u16*)(ws + 40 * MB);   // 8 MB  (32 x 64 x 2048)
  u16* Ob   = (u16*)(ws + 48 * MB);   // 8 MB

  prep_kernel<<<5120, 256, 0, stream>>>(
      x, xbf, Wq, Wk, Wv, Wo,
      Wcat, Wcat + 1024 * 1024, Wcat + 2 * 1024 * 1024, Wot);
  gemm_qkv_kernel<<<dim3(24, 32), 256, 0, stream>>>(
      xbf, Wcat, bq, bk, bv, QKb, Vtb);
  flash9_kernel<<<512, 512, 0, stream>>>(QKb, Vtb, Ob);
  gemm_out_kernel<<<dim3(16, 32), 256, 0, stream>>>(Ob, Wot, bo, (float*)d_out);
}

// Round 8
// 179.721 us; speedup vs baseline: 1.0419x; 1.0419x over previous
//
#include <hip/hip_runtime.h>

typedef unsigned short u16;
typedef unsigned int u32;

#define DM 1024
#define NH 16
#define DH 64
#define BB 2
#define TT 2048

// Q pre-scale: (1/sqrt(64)) * log2(e)
#define SCLQ 0.18033688f

using frag8  = __attribute__((ext_vector_type(8))) short;
using bf16x8 = __attribute__((ext_vector_type(8))) __bf16;
using f32x4  = __attribute__((ext_vector_type(4))) float;

__device__ inline u16 f2bf(float f) {
  union { float f; u32 u; } v; v.f = f;
  u32 r = v.u + 0x7fffu + ((v.u >> 16) & 1u);
  return (u16)(r >> 16);
}

__device__ inline f32x4 mfma_bf16(frag8 a, frag8 b, f32x4 c) {
  return __builtin_amdgcn_mfma_f32_16x16x32_bf16(
      __builtin_bit_cast(bf16x8, a), __builtin_bit_cast(bf16x8, b), c, 0, 0, 0);
}

// async global->LDS, 16B/lane; LDS dest = base + lane*16 (wave-uniform base)
__device__ inline void gld16(void* lds, const void* g) {
  __builtin_amdgcn_global_load_lds(
      (const __attribute__((address_space(1))) void*)g,
      (__attribute__((address_space(3))) void*)lds, 16, 0, 0);
}

// swizzled LDS index (u16 units): row = 8 chunks of 8 u16 (16B);
// stored chunk position = chunk ^ (row & 7)
__device__ inline int swi(int row, int chunk) {
  return row * 64 + ((chunk ^ (row & 7)) << 3);
}

// 128-wide tile index (u16 units), 16 chunks of 8 u16; low-3 chunk bits XOR row
__device__ inline int sidx128(int row, int col) {
  return row * 128 + ((((col >> 3) ^ (row & 7)) << 3) | (col & 7));
}

// ---------- fused prep: x -> bf16 (blocks 0..4095) + W transposes (4096..5119) ----------
__global__ __launch_bounds__(256) void prep_kernel(
    const float* __restrict__ X, u16* __restrict__ Y,
    const float* __restrict__ W0, const float* __restrict__ W1,
    const float* __restrict__ W2, const float* __restrict__ W3,
    u16* __restrict__ O0, u16* __restrict__ O1,
    u16* __restrict__ O2, u16* __restrict__ O3) {
  int tid = threadIdx.x;
  if (blockIdx.x < 4096) {
    int i = blockIdx.x * 256 + tid;
    float4 v = ((const float4*)X)[i];
    ushort4 o;
    o.x = f2bf(v.x); o.y = f2bf(v.y); o.z = f2bf(v.z); o.w = f2bf(v.w);
    ((ushort4*)Y)[i] = o;
    return;
  }
  int id = blockIdx.x - 4096;          // 0..1023
  int z = id >> 8;                     // 0..3
  int rem = id & 255;
  const float* W; u16* Ot;
  switch (z) {
    case 0: W = W0; Ot = O0; break;
    case 1: W = W1; Ot = O1; break;
    case 2: W = W2; Ot = O2; break;
    default: W = W3; Ot = O3; break;
  }
  __shared__ u16 Ls[64][72];
  int n0 = (rem & 15) * 64;
  int k0 = (rem >> 4) * 64;
#pragma unroll
  for (int p = 0; p < 4; ++p) {
    int iid = tid + p * 256;
    int row = iid >> 4;
    int c4 = (iid & 15) * 4;
    float4 v = *(const float4*)&W[(size_t)(k0 + row) * DM + n0 + c4];
    ushort4 o; o.x = f2bf(v.x); o.y = f2bf(v.y); o.z = f2bf(v.z); o.w = f2bf(v.w);
    *(ushort4*)&Ls[row][c4] = o;
  }
  __syncthreads();
#pragma unroll
  for (int p = 0; p < 4; ++p) {
    int iid = tid + p * 256;
    int row = iid >> 4;
    int c4 = (iid & 15) * 4;
    ushort4 o;
    o.x = Ls[c4 + 0][row]; o.y = Ls[c4 + 1][row];
    o.z = Ls[c4 + 2][row]; o.w = Ls[c4 + 3][row];
    *(ushort4*)&Ot[(size_t)(n0 + row) * DM + k0 + c4] = o;
  }
}

// ---------- QKV GEMM: 128x128 tile, 3-deep counted-vmcnt pipeline ----------
__global__ __launch_bounds__(256, 3) void gemm_qkv_kernel(
    const u16* __restrict__ A, const u16* __restrict__ Bt,
    const float* __restrict__ b0, const float* __restrict__ b1,
    const float* __restrict__ b2,
    u16* __restrict__ QK, u16* __restrict__ Vt) {
  constexpr int K = 1024;
  constexpr int NT = 32;
  __shared__ u16 sm[24576];      // As: 3 x 4096, Bs: 3 x 4096 (48 KB); epi: 16384
  int tid = threadIdx.x;
  int lane = tid & 63, w = tid >> 6;
  int qd = lane >> 4, ln = lane & 15;
  int wm = (w & 1) * 64, wn = (w >> 1) * 64;
  // XCD-chunked remap: xcd -> 8M x 12N supertile; bijective over 32x24 grid.
  int lin = blockIdx.y * 24 + blockIdx.x;
  int xcd = lin & 7, j = lin >> 3;             // j in 0..95
  int m_idx = ((xcd >> 1) << 3) | (j & 7);     // 0..31
  int n_idx = (xcd & 1) * 12 + (j >> 3);       // 0..23
  int m0 = m_idx * 128, n0 = n_idx * 128;
  f32x4 z = {0.f, 0.f, 0.f, 0.f};
  f32x4 acc[4][4];
#pragma unroll
  for (int mi = 0; mi < 4; ++mi)
#pragma unroll
    for (int ni = 0; ni < 4; ++ni) acc[mi][ni] = z;

  const u16* ga = A + (size_t)(m0 + w * 32 + (lane >> 2)) * K + (lane & 3) * 8;
  const u16* gb = Bt + (size_t)(n0 + w * 32 + (lane >> 2)) * K + (lane & 3) * 8;

  auto stage = [&](int t, int buf) {
    u16* Ab = sm + buf * 4096;
    u16* Bb = sm + 12288 + buf * 4096;
    gld16(&Ab[w * 1024],       ga + t * 32);
    gld16(&Ab[w * 1024 + 512], ga + t * 32 + 16 * K);
    gld16(&Bb[w * 1024],       gb + t * 32);
    gld16(&Bb[w * 1024 + 512], gb + t * 32 + 16 * K);
  };

  stage(0, 0);
  stage(1, 1);

  int cur = 0, nbuf = 2;
  for (int t = 0; t < NT; ++t) {
    if (t < NT - 1) {
      asm volatile("s_waitcnt vmcnt(4)" ::: "memory");
    } else {
      asm volatile("s_waitcnt vmcnt(0)" ::: "memory");
    }
    __builtin_amdgcn_sched_barrier(0);
    __builtin_amdgcn_s_barrier();
    if (t + 2 < NT) {
      stage(t + 2, nbuf);
      nbuf = (nbuf == 2) ? 0 : nbuf + 1;
    }
    const u16* Ab = sm + cur * 4096;
    const u16* Bb = sm + 12288 + cur * 4096;
    frag8 af[4], bfr[4];
#pragma unroll
    for (int mi = 0; mi < 4; ++mi)
      af[mi] = *(const frag8*)&Ab[(wm + mi * 16 + ln) * 32 + qd * 8];
#pragma unroll
    for (int ni = 0; ni < 4; ++ni)
      bfr[ni] = *(const frag8*)&Bb[(wn + ni * 16 + ln) * 32 + qd * 8];
    __builtin_amdgcn_s_setprio(1);
#pragma unroll
    for (int mi = 0; mi < 4; ++mi)
#pragma unroll
      for (int ni = 0; ni < 4; ++ni)
        acc[mi][ni] = mfma_bf16(af[mi], bfr[ni], acc[mi][ni]);
    __builtin_amdgcn_s_setprio(0);
    cur = (cur == 2) ? 0 : cur + 1;
  }

  __syncthreads();  // done reading staging buffers; sm is free for the epilogue

  if (n0 < 2048) {
    bool isq = (n0 < 1024);
#pragma unroll
    for (int ni = 0; ni < 4; ++ni) {
      int c_loc = wn + ni * 16 + ln;
      int col = n0 + c_loc;
      float bias = isq ? b0[col] : b1[col - 1024];
#pragma unroll
      for (int mi = 0; mi < 4; ++mi) {
        int rbase = wm + mi * 16 + qd * 4;
#pragma unroll
        for (int r = 0; r < 4; ++r) {
          float v = acc[mi][ni][r] + bias;
          if (isq) v *= SCLQ;
          sm[sidx128(rbase + r, c_loc)] = f2bf(v);
        }
      }
    }
    __syncthreads();
#pragma unroll
    for (int p = 0; p < 8; ++p) {
      int id = p * 256 + tid;
      int tr = id >> 4, cr = id & 15;
      uint4 v = *(const uint4*)&sm[tr * 128 + ((cr ^ (tr & 7)) << 3)];
      *(uint4*)&QK[(size_t)(m0 + tr) * 2048 + n0 + cr * 8] = v;
    }
  } else {
    int b = m0 >> 11, tb = m0 & 2047;
    int n0v = n0 - 2048;
#pragma unroll
    for (int ni = 0; ni < 4; ++ni) {
      int c_loc = wn + ni * 16 + ln;       // d index within 128-col block
      float bias = b2[n0v + c_loc];
#pragma unroll
      for (int mi = 0; mi < 4; ++mi) {
        int tbase = wm + mi * 16 + qd * 4;
        u32 lo = ((u32)f2bf(acc[mi][ni][1] + bias) << 16) | f2bf(acc[mi][ni][0] + bias);
        u32 hi = ((u32)f2bf(acc[mi][ni][3] + bias) << 16) | f2bf(acc[mi][ni][2] + bias);
        uint2 pk; pk.x = lo; pk.y = hi;
        int idx = c_loc * 128 + ((((tbase >> 3) ^ (c_loc & 7)) << 3) | (tbase & 7));
        *(uint2*)&sm[idx] = pk;
      }
    }
    __syncthreads();
#pragma unroll
    for (int p = 0; p < 8; ++p) {
      int id = p * 256 + tid;
      int d_loc = id >> 4, tc = id & 15;
      uint4 v = *(const uint4*)&sm[d_loc * 128 + ((tc ^ (d_loc & 7)) << 3)];
      *(uint4*)&Vt[(size_t)(b * 1024 + n0v + d_loc) * 2048 + tb + tc * 8] = v;
    }
  }
}

// ---------- out-proj GEMM: 128x64 tile, 3-deep counted-vmcnt pipeline ----------
__global__ __launch_bounds__(256) void gemm_out_kernel(
    const u16* __restrict__ A, const u16* __restrict__ Bt,
    const float* __restrict__ b0, float* __restrict__ Cf) {
  constexpr int K = 1024;
  constexpr int NT = 32;
  __shared__ u16 sm[18432];    // As: 3 x 4096, Bs: 3 x 2048 (36 KB)
  int tid = threadIdx.x;
  int lane = tid & 63, w = tid >> 6;
  int qd = lane >> 4, ln = lane & 15;
  int lin = blockIdx.y * 16 + blockIdx.x;
  int xcd = lin & 7, j = lin >> 3;             // j in 0..63
  int m_idx = ((xcd >> 1) << 3) | (j & 7);     // 0..31
  int n_idx = ((xcd & 1) << 3) | (j >> 3);     // 0..15
  int m0 = m_idx * 128, n0 = n_idx * 64;
  f32x4 z = {0.f, 0.f, 0.f, 0.f};
  f32x4 acc[2][4];
#pragma unroll
  for (int mi = 0; mi < 2; ++mi)
#pragma unroll
    for (int ni = 0; ni < 4; ++ni) acc[mi][ni] = z;

  const u16* ga = A + (size_t)(m0 + w * 32 + (lane >> 2)) * K + (lane & 3) * 8;
  const u16* gb = Bt + (size_t)(n0 + w * 16 + (lane >> 2)) * K + (lane & 3) * 8;

  auto stage = [&](int t, int buf) {
    u16* Ab = sm + buf * 4096;
    u16* Bb = sm + 12288 + buf * 2048;
    gld16(&Ab[w * 1024],       ga + t * 32);
    gld16(&Ab[w * 1024 + 512], ga + t * 32 + 16 * K);
    gld16(&Bb[w * 512],        gb + t * 32);
  };

  stage(0, 0);
  stage(1, 1);

  int cur = 0, nbuf = 2;
  for (int t = 0; t < NT; ++t) {
    if (t < NT - 1) {
      asm volatile("s_waitcnt vmcnt(3)" ::: "memory");
    } else {
      asm volatile("s_waitcnt vmcnt(0)" ::: "memory");
    }
    __builtin_amdgcn_sched_barrier(0);
    __builtin_amdgcn_s_barrier();
    if (t + 2 < NT) {
      stage(t + 2, nbuf);
      nbuf = (nbuf == 2) ? 0 : nbuf + 1;
    }
    const u16* Ab = sm + cur * 4096;
    const u16* Bb = sm + 12288 + cur * 2048;
    frag8 af[2], bfr[4];
#pragma unroll
    for (int mi = 0; mi < 2; ++mi)
      af[mi] = *(const frag8*)&Ab[(w * 32 + mi * 16 + ln) * 32 + qd * 8];
#pragma unroll
    for (int ni = 0; ni < 4; ++ni)
      bfr[ni] = *(const frag8*)&Bb[(ni * 16 + ln) * 32 + qd * 8];
    __builtin_amdgcn_s_setprio(1);
#pragma unroll
    for (int mi = 0; mi < 2; ++mi)
#pragma unroll
      for (int ni = 0; ni < 4; ++ni)
        acc[mi][ni] = mfma_bf16(af[mi], bfr[ni], acc[mi][ni]);
    __builtin_amdgcn_s_setprio(0);
    cur = (cur == 2) ? 0 : cur + 1;
  }

#pragma unroll
  for (int ni = 0; ni < 4; ++ni) {
    int col = n0 + ni * 16 + ln;
    float bias = b0[col];
#pragma unroll
    for (int mi = 0; mi < 2; ++mi) {
      int row = m0 + w * 32 + mi * 16 + qd * 4;
#pragma unroll
      for (int r = 0; r < 4; ++r)
        Cf[(size_t)(row + r) * 1024 + col] = acc[mi][ni][r] + bias;
    }
  }
}

// ---------- flash v10: v8 skeleton (REVERT of v9) + softmax fused into QK loop ----------
// ROUND-7 LESSON: QBLK=128 8-wave blocks (v9) regressed 40->51us. Mechanism:
// 4-wave x 4-block/CU gives each SIMD 4 waves from 4 DIFFERENT blocks at
// independent phases (cross-block pipe overlap); 8-wave x 2-block/CU leaves
// same-phase barrier-locked waves that can't hide each other's serial
// QK->SM->PV chain. More independent small blocks > fewer wide blocks.
// v10 change vs v8: softmax(mi) inlined right after s[mi]'s MFMAs and the
// setprio fence between QK and SM removed, letting the scheduler run mi's
// exp2/pack (VALU) under mi+1's MFMAs. Numerically identical.
// QK: [B*T][2048] bf16 (Q pre-scaled, K). Vt: [B*H][DH][TT]. O: [B*T][1024] bf16.
__global__ __launch_bounds__(256, 4) void flash10_kernel(const u16* __restrict__ QK,
                                                         const u16* __restrict__ Vt,
                                                         u16* __restrict__ O) {
  int lin = blockIdx.y * 32 + blockIdx.x;
  int xcd = lin & 7, u = lin >> 3;   // u in 0..127
  int a = u & 31, r = u >> 5;        // r in 0..3
  int bh = (xcd << 2) | r;
  int qt = (r & 1) ? (31 - a) : a;
  int b = bh >> 4, h = bh & 15;
  int q0 = qt * 64;
  __shared__ u16 Ks[2 * 4096];
  __shared__ u16 Vs[2 * 4096];
  __shared__ u16 Ps[4096];
  int tid = threadIdx.x;
  int lane = tid & 63, w = tid >> 6;
  int qd = lane >> 4, ln = lane & 15;

  // Q fragments (B-operand: n=ln -> q, k=qd*8+j -> d); Q pre-scaled by SCLQ
  frag8 qf[2];
#pragma unroll
  for (int kk = 0; kk < 2; ++kk)
    qf[kk] = *(const frag8*)&QK[(size_t)(b * TT + q0 + w * 16 + ln) * 2048 +
                                h * 64 + kk * 32 + qd * 8];

  // swizzled global_load_lds staging (content chunk xor'ed into source addr)
  int lr = lane >> 3, lc = (lane & 7) ^ lr;
  const u16* Kg  = &QK[(size_t)(b * TT + w * 16 + lr) * 2048 + 1024 + h * 64 + lc * 8];
  const u16* Kg2 = Kg + 8 * 2048;
  const u16* Vg  = &Vt[(size_t)(bh * 64 + w * 16 + lr) * 2048 + lc * 8];
  const u16* Vg2 = Vg + 8 * 2048;
  int ldsw = w * 1024;

  int nkt = qt + 1;

  gld16(&Ks[ldsw],       Kg);
  gld16(&Ks[ldsw + 512], Kg2);
  gld16(&Vs[ldsw],       Vg);
  gld16(&Vs[ldsw + 512], Vg2);

  float l = 0.f;
  f32x4 z = {0.f, 0.f, 0.f, 0.f};
  f32x4 o[4] = {z, z, z, z};

  for (int kt = 0; kt < nkt; ++kt) {
    int cur = kt & 1;
    int cb = cur * 4096;
    __syncthreads();  // drains prefetch for buf[cur]; prior reads of buf[cur^1] done

    if (kt + 1 < nkt) {
      int nb = (cur ^ 1) * 4096;
      size_t ko = (size_t)(kt + 1) * 64 * 2048;
      int vo = (kt + 1) * 64;
      gld16(&Ks[nb + ldsw],       Kg + ko);
      gld16(&Ks[nb + ldsw + 512], Kg2 + ko);
      gld16(&Vs[nb + ldsw],       Vg + vo);
      gld16(&Vs[nb + ldsw + 512], Vg2 + vo);
    }

    bool diag = (kt == qt);

    // S^T = K Q^T with softmax(mi) fused in (VALU overlaps next mi's MFMAs)
#pragma unroll
    for (int mi = 0; mi < 4; ++mi) {
      int pb = swi(w * 16 + ln, 2 * mi + (qd >> 1)) + (qd & 1) * 4;
      if (diag && mi > w) {
        uint2 zz; zz.x = 0u; zz.y = 0u;
        *(uint2*)&Ps[pb] = zz;
        continue;
      }
      f32x4 s = z;
#pragma unroll
      for (int kk = 0; kk < 2; ++kk) {
        frag8 ak = *(const frag8*)&Ks[cb + swi(mi * 16 + ln, 4 * kk + qd)];
        s = mfma_bf16(ak, qf[kk], s);
      }
      float p0 = __builtin_amdgcn_exp2f(s[0]);
      float p1 = __builtin_amdgcn_exp2f(s[1]);
      float p2 = __builtin_amdgcn_exp2f(s[2]);
      float p3 = __builtin_amdgcn_exp2f(s[3]);
      if (diag && mi == w) {
        p0 = (qd * 4 + 0 <= ln) ? p0 : 0.f;
        p1 = (qd * 4 + 1 <= ln) ? p1 : 0.f;
        p2 = (qd * 4 + 2 <= ln) ? p2 : 0.f;
        p3 = (qd * 4 + 3 <= ln) ? p3 : 0.f;
      }
      l += (p0 + p1) + (p2 + p3);
      u32 u0 = __builtin_bit_cast(u32, p0) + 0x8000u;
      u32 u1 = __builtin_bit_cast(u32, p1) + 0x8000u;
      u32 u2 = __builtin_bit_cast(u32, p2) + 0x8000u;
      u32 u3 = __builtin_bit_cast(u32, p3) + 0x8000u;
      uint2 pk;
      pk.x = __builtin_amdgcn_perm(u1, u0, 0x07060302u);
      pk.y = __builtin_amdgcn_perm(u3, u2, 0x07060302u);
      *(uint2*)&Ps[pb] = pk;
    }

    // O^T += V^T P^T
    __builtin_amdgcn_s_setprio(1);
#pragma unroll
    for (int kk = 0; kk < 2; ++kk) {
      if (diag && kk == 1 && w < 2) continue;  // fully-masked k-half
      frag8 bp = *(const frag8*)&Ps[swi(w * 16 + ln, 4 * kk + qd)];
#pragma unroll
      for (int mi = 0; mi < 4; ++mi) {
        frag8 av = *(const frag8*)&Vs[cb + swi(mi * 16 + ln, 4 * kk + qd)];
        o[mi] = mfma_bf16(av, bp, o[mi]);
      }
    }
    __builtin_amdgcn_s_setprio(0);
  }

  l += __shfl_xor(l, 16);
  l += __shfl_xor(l, 32);
  float rl = 1.0f / l;

#pragma unroll
  for (int mi = 0; mi < 4; ++mi) {
    ushort4 ov;
    ov.x = f2bf(o[mi][0] * rl); ov.y = f2bf(o[mi][1] * rl);
    ov.z = f2bf(o[mi][2] * rl); ov.w = f2bf(o[mi][3] * rl);
    *(ushort4*)&O[(size_t)(b * TT + q0 + w * 16 + ln) * DM + h * 64 + mi * 16 + qd * 4] = ov;
  }
}

extern "C" void kernel_launch(void* const* d_in, const int* in_sizes, int n_in,
                              void* d_out, int out_size, void* d_ws, size_t ws_size,
                              hipStream_t stream) {
  const float* x  = (const float*)d_in[0];
  const float* Wq = (const float*)d_in[1];
  const float* bq = (const float*)d_in[2];
  const float* Wk = (const float*)d_in[3];
  const float* bk = (const float*)d_in[4];
  const float* Wv = (const float*)d_in[5];
  const float* bv = (const float*)d_in[6];
  const float* Wo = (const float*)d_in[7];
  const float* bo = (const float*)d_in[8];

  char* ws = (char*)d_ws;
  const size_t MB = 1ull << 20;
  u16* xbf  = (u16*)(ws + 0);         // 8 MB  (4096 x 1024)
  u16* Wcat = (u16*)(ws + 8 * MB);    // 6 MB  (3072 x 1024: Wq^T|Wk^T|Wv^T)
  u16* Wot  = (u16*)(ws + 14 * MB);   // 2 MB
  u16* QKb  = (u16*)(ws + 16 * MB);   // 16 MB (4096 x 2048)
  u16* Vtb  = (u16*)(ws + 40 * MB);   // 8 MB  (32 x 64 x 2048)
  u16* Ob   = (u16*)(ws + 48 * MB);   // 8 MB

  prep_kernel<<<5120, 256, 0, stream>>>(
      x, xbf, Wq, Wk, Wv, Wo,
      Wcat, Wcat + 1024 * 1024, Wcat + 2 * 1024 * 1024, Wot);
  gemm_qkv_kernel<<<dim3(24, 32), 256, 0, stream>>>(
      xbf, Wcat, bq, bk, bv, QKb, Vtb);
  flash10_kernel<<<dim3(32, 32), 256, 0, stream>>>(QKb, Vtb, Ob);
  gemm_out_kernel<<<dim3(16, 32), 256, 0, stream>>>(Ob, Wot, bo, (float*)d_out);
}

// Round 9
// 175.430 us; speedup vs baseline: 1.0674x; 1.0245x over previous
//
#include <hip/hip_runtime.h>

typedef unsigned short u16;
typedef unsigned int u32;

#define DM 1024
#define NH 16
#define DH 64
#define BB 2
#define TT 2048

// Q pre-scale: (1/sqrt(64)) * log2(e)
#define SCLQ 0.18033688f

using frag8  = __attribute__((ext_vector_type(8))) short;
using bf16x8 = __attribute__((ext_vector_type(8))) __bf16;
using f32x4  = __attribute__((ext_vector_type(4))) float;

__device__ inline u16 f2bf(float f) {
  union { float f; u32 u; } v; v.f = f;
  u32 r = v.u + 0x7fffu + ((v.u >> 16) & 1u);
  return (u16)(r >> 16);
}

__device__ inline f32x4 mfma_bf16(frag8 a, frag8 b, f32x4 c) {
  return __builtin_amdgcn_mfma_f32_16x16x32_bf16(
      __builtin_bit_cast(bf16x8, a), __builtin_bit_cast(bf16x8, b), c, 0, 0, 0);
}

// async global->LDS, 16B/lane; LDS dest = base + lane*16 (wave-uniform base)
__device__ inline void gld16(void* lds, const void* g) {
  __builtin_amdgcn_global_load_lds(
      (const __attribute__((address_space(1))) void*)g,
      (__attribute__((address_space(3))) void*)lds, 16, 0, 0);
}

// swizzled LDS index (u16 units): row = 8 chunks of 8 u16 (16B);
// stored chunk position = chunk ^ (row & 7)
__device__ inline int swi(int row, int chunk) {
  return row * 64 + ((chunk ^ (row & 7)) << 3);
}

// 128-wide tile index (u16 units), 16 chunks of 8 u16; low-3 chunk bits XOR row
__device__ inline int sidx128(int row, int col) {
  return row * 128 + ((((col >> 3) ^ (row & 7)) << 3) | (col & 7));
}

// ---------- fused prep: x -> bf16 (blocks 0..4095) + W transposes (4096..5119) ----------
__global__ __launch_bounds__(256) void prep_kernel(
    const float* __restrict__ X, u16* __restrict__ Y,
    const float* __restrict__ W0, const float* __restrict__ W1,
    const float* __restrict__ W2, const float* __restrict__ W3,
    u16* __restrict__ O0, u16* __restrict__ O1,
    u16* __restrict__ O2, u16* __restrict__ O3) {
  int tid = threadIdx.x;
  if (blockIdx.x < 4096) {
    int i = blockIdx.x * 256 + tid;
    float4 v = ((const float4*)X)[i];
    ushort4 o;
    o.x = f2bf(v.x); o.y = f2bf(v.y); o.z = f2bf(v.z); o.w = f2bf(v.w);
    ((ushort4*)Y)[i] = o;
    return;
  }
  int id = blockIdx.x - 4096;          // 0..1023
  int z = id >> 8;                     // 0..3
  int rem = id & 255;
  const float* W; u16* Ot;
  switch (z) {
    case 0: W = W0; Ot = O0; break;
    case 1: W = W1; Ot = O1; break;
    case 2: W = W2; Ot = O2; break;
    default: W = W3; Ot = O3; break;
  }
  __shared__ u16 Ls[64][72];
  int n0 = (rem & 15) * 64;
  int k0 = (rem >> 4) * 64;
#pragma unroll
  for (int p = 0; p < 4; ++p) {
    int iid = tid + p * 256;
    int row = iid >> 4;
    int c4 = (iid & 15) * 4;
    float4 v = *(const float4*)&W[(size_t)(k0 + row) * DM + n0 + c4];
    ushort4 o; o.x = f2bf(v.x); o.y = f2bf(v.y); o.z = f2bf(v.z); o.w = f2bf(v.w);
    *(ushort4*)&Ls[row][c4] = o;
  }
  __syncthreads();
#pragma unroll
  for (int p = 0; p < 4; ++p) {
    int iid = tid + p * 256;
    int row = iid >> 4;
    int c4 = (iid & 15) * 4;
    ushort4 o;
    o.x = Ls[c4 + 0][row]; o.y = Ls[c4 + 1][row];
    o.z = Ls[c4 + 2][row]; o.w = Ls[c4 + 3][row];
    *(ushort4*)&Ot[(size_t)(n0 + row) * DM + k0 + c4] = o;
  }
}

// ---------- QKV GEMM: 128x128 tile, 3-deep counted-vmcnt pipeline ----------
__global__ __launch_bounds__(256, 3) void gemm_qkv_kernel(
    const u16* __restrict__ A, const u16* __restrict__ Bt,
    const float* __restrict__ b0, const float* __restrict__ b1,
    const float* __restrict__ b2,
    u16* __restrict__ QK, u16* __restrict__ Vt) {
  constexpr int K = 1024;
  constexpr int NT = 32;
  __shared__ u16 sm[24576];      // As: 3 x 4096, Bs: 3 x 4096 (48 KB); epi: 16384
  int tid = threadIdx.x;
  int lane = tid & 63, w = tid >> 6;
  int qd = lane >> 4, ln = lane & 15;
  int wm = (w & 1) * 64, wn = (w >> 1) * 64;
  // XCD-chunked remap: xcd -> 8M x 12N supertile; bijective over 32x24 grid.
  int lin = blockIdx.y * 24 + blockIdx.x;
  int xcd = lin & 7, j = lin >> 3;             // j in 0..95
  int m_idx = ((xcd >> 1) << 3) | (j & 7);     // 0..31
  int n_idx = (xcd & 1) * 12 + (j >> 3);       // 0..23
  int m0 = m_idx * 128, n0 = n_idx * 128;
  f32x4 z = {0.f, 0.f, 0.f, 0.f};
  f32x4 acc[4][4];
#pragma unroll
  for (int mi = 0; mi < 4; ++mi)
#pragma unroll
    for (int ni = 0; ni < 4; ++ni) acc[mi][ni] = z;

  const u16* ga = A + (size_t)(m0 + w * 32 + (lane >> 2)) * K + (lane & 3) * 8;
  const u16* gb = Bt + (size_t)(n0 + w * 32 + (lane >> 2)) * K + (lane & 3) * 8;

  auto stage = [&](int t, int buf) {
    u16* Ab = sm + buf * 4096;
    u16* Bb = sm + 12288 + buf * 4096;
    gld16(&Ab[w * 1024],       ga + t * 32);
    gld16(&Ab[w * 1024 + 512], ga + t * 32 + 16 * K);
    gld16(&Bb[w * 1024],       gb + t * 32);
    gld16(&Bb[w * 1024 + 512], gb + t * 32 + 16 * K);
  };

  stage(0, 0);
  stage(1, 1);

  int cur = 0, nbuf = 2;
  for (int t = 0; t < NT; ++t) {
    if (t < NT - 1) {
      asm volatile("s_waitcnt vmcnt(4)" ::: "memory");
    } else {
      asm volatile("s_waitcnt vmcnt(0)" ::: "memory");
    }
    __builtin_amdgcn_sched_barrier(0);
    __builtin_amdgcn_s_barrier();
    if (t + 2 < NT) {
      stage(t + 2, nbuf);
      nbuf = (nbuf == 2) ? 0 : nbuf + 1;
    }
    const u16* Ab = sm + cur * 4096;
    const u16* Bb = sm + 12288 + cur * 4096;
    frag8 af[4], bfr[4];
#pragma unroll
    for (int mi = 0; mi < 4; ++mi)
      af[mi] = *(const frag8*)&Ab[(wm + mi * 16 + ln) * 32 + qd * 8];
#pragma unroll
    for (int ni = 0; ni < 4; ++ni)
      bfr[ni] = *(const frag8*)&Bb[(wn + ni * 16 + ln) * 32 + qd * 8];
    __builtin_amdgcn_s_setprio(1);
#pragma unroll
    for (int mi = 0; mi < 4; ++mi)
#pragma unroll
      for (int ni = 0; ni < 4; ++ni)
        acc[mi][ni] = mfma_bf16(af[mi], bfr[ni], acc[mi][ni]);
    __builtin_amdgcn_s_setprio(0);
    cur = (cur == 2) ? 0 : cur + 1;
  }

  __syncthreads();  // done reading staging buffers; sm is free for the epilogue

  if (n0 < 2048) {
    bool isq = (n0 < 1024);
#pragma unroll
    for (int ni = 0; ni < 4; ++ni) {
      int c_loc = wn + ni * 16 + ln;
      int col = n0 + c_loc;
      float bias = isq ? b0[col] : b1[col - 1024];
#pragma unroll
      for (int mi = 0; mi < 4; ++mi) {
        int rbase = wm + mi * 16 + qd * 4;
#pragma unroll
        for (int r = 0; r < 4; ++r) {
          float v = acc[mi][ni][r] + bias;
          if (isq) v *= SCLQ;
          sm[sidx128(rbase + r, c_loc)] = f2bf(v);
        }
      }
    }
    __syncthreads();
#pragma unroll
    for (int p = 0; p < 8; ++p) {
      int id = p * 256 + tid;
      int tr = id >> 4, cr = id & 15;
      uint4 v = *(const uint4*)&sm[tr * 128 + ((cr ^ (tr & 7)) << 3)];
      *(uint4*)&QK[(size_t)(m0 + tr) * 2048 + n0 + cr * 8] = v;
    }
  } else {
    int b = m0 >> 11, tb = m0 & 2047;
    int n0v = n0 - 2048;
#pragma unroll
    for (int ni = 0; ni < 4; ++ni) {
      int c_loc = wn + ni * 16 + ln;       // d index within 128-col block
      float bias = b2[n0v + c_loc];
#pragma unroll
      for (int mi = 0; mi < 4; ++mi) {
        int tbase = wm + mi * 16 + qd * 4;
        u32 lo = ((u32)f2bf(acc[mi][ni][1] + bias) << 16) | f2bf(acc[mi][ni][0] + bias);
        u32 hi = ((u32)f2bf(acc[mi][ni][3] + bias) << 16) | f2bf(acc[mi][ni][2] + bias);
        uint2 pk; pk.x = lo; pk.y = hi;
        int idx = c_loc * 128 + ((((tbase >> 3) ^ (c_loc & 7)) << 3) | (tbase & 7));
        *(uint2*)&sm[idx] = pk;
      }
    }
    __syncthreads();
#pragma unroll
    for (int p = 0; p < 8; ++p) {
      int id = p * 256 + tid;
      int d_loc = id >> 4, tc = id & 15;
      uint4 v = *(const uint4*)&sm[d_loc * 128 + ((tc ^ (d_loc & 7)) << 3)];
      *(uint4*)&Vt[(size_t)(b * 1024 + n0v + d_loc) * 2048 + tb + tc * 8] = v;
    }
  }
}

// ---------- out-proj GEMM: 128x64 tile, 3-deep counted-vmcnt pipeline ----------
__global__ __launch_bounds__(256) void gemm_out_kernel(
    const u16* __restrict__ A, const u16* __restrict__ Bt,
    const float* __restrict__ b0, float* __restrict__ Cf) {
  constexpr int K = 1024;
  constexpr int NT = 32;
  __shared__ u16 sm[18432];    // As: 3 x 4096, Bs: 3 x 2048 (36 KB)
  int tid = threadIdx.x;
  int lane = tid & 63, w = tid >> 6;
  int qd = lane >> 4, ln = lane & 15;
  int lin = blockIdx.y * 16 + blockIdx.x;
  int xcd = lin & 7, j = lin >> 3;             // j in 0..63
  int m_idx = ((xcd >> 1) << 3) | (j & 7);     // 0..31
  int n_idx = ((xcd & 1) << 3) | (j >> 3);     // 0..15
  int m0 = m_idx * 128, n0 = n_idx * 64;
  f32x4 z = {0.f, 0.f, 0.f, 0.f};
  f32x4 acc[2][4];
#pragma unroll
  for (int mi = 0; mi < 2; ++mi)
#pragma unroll
    for (int ni = 0; ni < 4; ++ni) acc[mi][ni] = z;

  const u16* ga = A + (size_t)(m0 + w * 32 + (lane >> 2)) * K + (lane & 3) * 8;
  const u16* gb = Bt + (size_t)(n0 + w * 16 + (lane >> 2)) * K + (lane & 3) * 8;

  auto stage = [&](int t, int buf) {
    u16* Ab = sm + buf * 4096;
    u16* Bb = sm + 12288 + buf * 2048;
    gld16(&Ab[w * 1024],       ga + t * 32);
    gld16(&Ab[w * 1024 + 512], ga + t * 32 + 16 * K);
    gld16(&Bb[w * 512],        gb + t * 32);
  };

  stage(0, 0);
  stage(1, 1);

  int cur = 0, nbuf = 2;
  for (int t = 0; t < NT; ++t) {
    if (t < NT - 1) {
      asm volatile("s_waitcnt vmcnt(3)" ::: "memory");
    } else {
      asm volatile("s_waitcnt vmcnt(0)" ::: "memory");
    }
    __builtin_amdgcn_sched_barrier(0);
    __builtin_amdgcn_s_barrier();
    if (t + 2 < NT) {
      stage(t + 2, nbuf);
      nbuf = (nbuf == 2) ? 0 : nbuf + 1;
    }
    const u16* Ab = sm + cur * 4096;
    const u16* Bb = sm + 12288 + cur * 2048;
    frag8 af[2], bfr[4];
#pragma unroll
    for (int mi = 0; mi < 2; ++mi)
      af[mi] = *(const frag8*)&Ab[(w * 32 + mi * 16 + ln) * 32 + qd * 8];
#pragma unroll
    for (int ni = 0; ni < 4; ++ni)
      bfr[ni] = *(const frag8*)&Bb[(ni * 16 + ln) * 32 + qd * 8];
    __builtin_amdgcn_s_setprio(1);
#pragma unroll
    for (int mi = 0; mi < 2; ++mi)
#pragma unroll
      for (int ni = 0; ni < 4; ++ni)
        acc[mi][ni] = mfma_bf16(af[mi], bfr[ni], acc[mi][ni]);
    __builtin_amdgcn_s_setprio(0);
    cur = (cur == 2) ? 0 : cur + 1;
  }

#pragma unroll
  for (int ni = 0; ni < 4; ++ni) {
    int col = n0 + ni * 16 + ln;
    float bias = b0[col];
#pragma unroll
    for (int mi = 0; mi < 2; ++mi) {
      int row = m0 + w * 32 + mi * 16 + qd * 4;
#pragma unroll
      for (int r = 0; r < 4; ++r)
        Cf[(size_t)(row + r) * 1024 + col] = acc[mi][ni][r] + bias;
    }
  }
}

// ---------- flash v8 (RESTORED round-6 best): XCD-chunked (b,h), balanced qt,
// separate QK -> SM -> PV phases with setprio fences, manual RNE pack ----------
// ROUND-7 LESSON: 8-wave QBLK=128 blocks regressed (same-phase barrier-locked
// waves can't hide each other's serial chain). ROUND-8 LESSON: fusing SM into
// the QK mi-loop + dropping QK setprio regressed 4us (Ps ds_writes inside the
// MFMA cluster break clustering; LDS-port contention during compute). This
// exact phase-separated form measured 175.7us total.
// QK: [B*T][2048] bf16 (Q pre-scaled, K). Vt: [B*H][DH][TT]. O: [B*T][1024] bf16.
__global__ __launch_bounds__(256, 4) void flash8_kernel(const u16* __restrict__ QK,
                                                        const u16* __restrict__ Vt,
                                                        u16* __restrict__ O) {
  int lin = blockIdx.y * 32 + blockIdx.x;
  int xcd = lin & 7, u = lin >> 3;   // u in 0..127
  int a = u & 31, r = u >> 5;        // r in 0..3
  int bh = (xcd << 2) | r;
  int qt = (r & 1) ? (31 - a) : a;
  int b = bh >> 4, h = bh & 15;
  int q0 = qt * 64;
  __shared__ u16 Ks[2 * 4096];
  __shared__ u16 Vs[2 * 4096];
  __shared__ u16 Ps[4096];
  int tid = threadIdx.x;
  int lane = tid & 63, w = tid >> 6;
  int qd = lane >> 4, ln = lane & 15;

  // Q fragments (B-operand: n=ln -> q, k=qd*8+j -> d); Q pre-scaled by SCLQ
  frag8 qf[2];
#pragma unroll
  for (int kk = 0; kk < 2; ++kk)
    qf[kk] = *(const frag8*)&QK[(size_t)(b * TT + q0 + w * 16 + ln) * 2048 +
                                h * 64 + kk * 32 + qd * 8];

  // swizzled global_load_lds staging (content chunk xor'ed into source addr)
  int lr = lane >> 3, lc = (lane & 7) ^ lr;
  const u16* Kg  = &QK[(size_t)(b * TT + w * 16 + lr) * 2048 + 1024 + h * 64 + lc * 8];
  const u16* Kg2 = Kg + 8 * 2048;
  const u16* Vg  = &Vt[(size_t)(bh * 64 + w * 16 + lr) * 2048 + lc * 8];
  const u16* Vg2 = Vg + 8 * 2048;
  int ldsw = w * 1024;

  int nkt = qt + 1;

  gld16(&Ks[ldsw],       Kg);
  gld16(&Ks[ldsw + 512], Kg2);
  gld16(&Vs[ldsw],       Vg);
  gld16(&Vs[ldsw + 512], Vg2);

  float l = 0.f;
  f32x4 z = {0.f, 0.f, 0.f, 0.f};
  f32x4 o[4] = {z, z, z, z};

  for (int kt = 0; kt < nkt; ++kt) {
    int cur = kt & 1;
    int cb = cur * 4096;
    __syncthreads();  // drains prefetch for buf[cur]; prior reads of buf[cur^1] done

    if (kt + 1 < nkt) {
      int nb = (cur ^ 1) * 4096;
      size_t ko = (size_t)(kt + 1) * 64 * 2048;
      int vo = (kt + 1) * 64;
      gld16(&Ks[nb + ldsw],       Kg + ko);
      gld16(&Ks[nb + ldsw + 512], Kg2 + ko);
      gld16(&Vs[nb + ldsw],       Vg + vo);
      gld16(&Vs[nb + ldsw + 512], Vg2 + vo);
    }

    bool diag = (kt == qt);

    // S^T = K Q^T
    f32x4 s[4] = {z, z, z, z};
    __builtin_amdgcn_s_setprio(1);
#pragma unroll
    for (int mi = 0; mi < 4; ++mi) {
      if (diag && mi > w) continue;  // fully-masked k-rows
#pragma unroll
      for (int kk = 0; kk < 2; ++kk) {
        frag8 ak = *(const frag8*)&Ks[cb + swi(mi * 16 + ln, 4 * kk + qd)];
        s[mi] = mfma_bf16(ak, qf[kk], s[mi]);
      }
    }
    __builtin_amdgcn_s_setprio(0);

    // fixed-max softmax + manual RNE bf16 pack into P^T LDS (own-wave rows only)
#pragma unroll
    for (int mi = 0; mi < 4; ++mi) {
      int pb = swi(w * 16 + ln, 2 * mi + (qd >> 1)) + (qd & 1) * 4;
      if (diag && mi > w) {
        uint2 zz; zz.x = 0u; zz.y = 0u;
        *(uint2*)&Ps[pb] = zz;
        continue;
      }
      float p0 = __builtin_amdgcn_exp2f(s[mi][0]);
      float p1 = __builtin_amdgcn_exp2f(s[mi][1]);
      float p2 = __builtin_amdgcn_exp2f(s[mi][2]);
      float p3 = __builtin_amdgcn_exp2f(s[mi][3]);
      if (diag && mi == w) {
        p0 = (qd * 4 + 0 <= ln) ? p0 : 0.f;
        p1 = (qd * 4 + 1 <= ln) ? p1 : 0.f;
        p2 = (qd * 4 + 2 <= ln) ? p2 : 0.f;
        p3 = (qd * 4 + 3 <= ln) ? p3 : 0.f;
      }
      l += (p0 + p1) + (p2 + p3);
      u32 u0 = __builtin_bit_cast(u32, p0) + 0x8000u;
      u32 u1 = __builtin_bit_cast(u32, p1) + 0x8000u;
      u32 u2 = __builtin_bit_cast(u32, p2) + 0x8000u;
      u32 u3 = __builtin_bit_cast(u32, p3) + 0x8000u;
      uint2 pk;
      pk.x = __builtin_amdgcn_perm(u1, u0, 0x07060302u);
      pk.y = __builtin_amdgcn_perm(u3, u2, 0x07060302u);
      *(uint2*)&Ps[pb] = pk;
    }

    // O^T += V^T P^T
    __builtin_amdgcn_s_setprio(1);
#pragma unroll
    for (int kk = 0; kk < 2; ++kk) {
      if (diag && kk == 1 && w < 2) continue;  // fully-masked k-half
      frag8 bp = *(const frag8*)&Ps[swi(w * 16 + ln, 4 * kk + qd)];
#pragma unroll
      for (int mi = 0; mi < 4; ++mi) {
        frag8 av = *(const frag8*)&Vs[cb + swi(mi * 16 + ln, 4 * kk + qd)];
        o[mi] = mfma_bf16(av, bp, o[mi]);
      }
    }
    __builtin_amdgcn_s_setprio(0);
  }

  l += __shfl_xor(l, 16);
  l += __shfl_xor(l, 32);
  float rl = 1.0f / l;

#pragma unroll
  for (int mi = 0; mi < 4; ++mi) {
    ushort4 ov;
    ov.x = f2bf(o[mi][0] * rl); ov.y = f2bf(o[mi][1] * rl);
    ov.z = f2bf(o[mi][2] * rl); ov.w = f2bf(o[mi][3] * rl);
    *(ushort4*)&O[(size_t)(b * TT + q0 + w * 16 + ln) * DM + h * 64 + mi * 16 + qd * 4] = ov;
  }
}

extern "C" void kernel_launch(void* const* d_in, const int* in_sizes, int n_in,
                              void* d_out, int out_size, void* d_ws, size_t ws_size,
                              hipStream_t stream) {
  const float* x  = (const float*)d_in[0];
  const float* Wq = (const float*)d_in[1];
  const float* bq = (const float*)d_in[2];
  const float* Wk = (const float*)d_in[3];
  const float* bk = (const float*)d_in[4];
  const float* Wv = (const float*)d_in[5];
  const float* bv = (const float*)d_in[6];
  const float* Wo = (const float*)d_in[7];
  const float* bo = (const float*)d_in[8];

  char* ws = (char*)d_ws;
  const size_t MB = 1ull << 20;
  u16* xbf  = (u16*)(ws + 0);         // 8 MB  (4096 x 1024)
  u16* Wcat = (u16*)(ws + 8 * MB);    // 6 MB  (3072 x 1024: Wq^T|Wk^T|Wv^T)
  u16* Wot  = (u16*)(ws + 14 * MB);   // 2 MB
  u16* QKb  = (u16*)(ws + 16 * MB);   // 16 MB (4096 x 2048)
  u16* Vtb  = (u16*)(ws + 40 * MB);   // 8 MB  (32 x 64 x 2048)
  u16* Ob   = (u16*)(ws + 48 * MB);   // 8 MB

  prep_kernel<<<5120, 256, 0, stream>>>(
      x, xbf, Wq, Wk, Wv, Wo,
      Wcat, Wcat + 1024 * 1024, Wcat + 2 * 1024 * 1024, Wot);
  gemm_qkv_kernel<<<dim3(24, 32), 256, 0, stream>>>(
      xbf, Wcat, bq, bk, bv, QKb, Vtb);
  flash8_kernel<<<dim3(32, 32), 256, 0, stream>>>(QKb, Vtb, Ob);
  gemm_out_kernel<<<dim3(16, 32), 256, 0, stream>>>(Ob, Wot, bo, (float*)d_out);
}